// Round 5
// baseline (1104.971 us; speedup 1.0000x reference)
//
#include <hip/hip_runtime.h>
#include <hip/hip_bf16.h>
#include <cstdint>
#include <cstddef>

typedef __bf16 bf16_t;
typedef __bf16 bf16x8 __attribute__((ext_vector_type(8)));
typedef float  f32x4  __attribute__((ext_vector_type(4)));

#define TOKENS 16384
#define HIDDEN 2048
#define FFN    8192

// ---------------------------------------------------------------------------
// async global -> LDS, 16B per lane (wave-uniform LDS base + lane*16)
// ---------------------------------------------------------------------------
__device__ __forceinline__ void gload_lds16(const bf16_t* g, bf16_t* l) {
    __builtin_amdgcn_global_load_lds((const __attribute__((address_space(1))) void*)g,
                                     (__attribute__((address_space(3))) void*)l,
                                     16, 0, 0);
}

// ---------------------------------------------------------------------------
// f32 -> bf16 elementwise convert, 8 elems/thread
// ---------------------------------------------------------------------------
__global__ void cvt_f32_to_bf16(const float* __restrict__ in, bf16_t* __restrict__ out, int n8) {
    int i = blockIdx.x * blockDim.x + threadIdx.x;
    if (i >= n8) return;
    size_t base = (size_t)i * 8;
    f32x4 v0 = *(const f32x4*)&in[base];
    f32x4 v1 = *(const f32x4*)&in[base + 4];
    bf16x8 o;
    o[0] = (bf16_t)v0[0]; o[1] = (bf16_t)v0[1]; o[2] = (bf16_t)v0[2]; o[3] = (bf16_t)v0[3];
    o[4] = (bf16_t)v1[0]; o[5] = (bf16_t)v1[1]; o[6] = (bf16_t)v1[2]; o[7] = (bf16_t)v1[3];
    *(bf16x8*)&out[base] = o;
}

// ---------------------------------------------------------------------------
// Transpose + convert: src (R x C f32) -> dst (C x R bf16)
// ---------------------------------------------------------------------------
__global__ void transpose_cvt(const float* __restrict__ src, bf16_t* __restrict__ dst,
                              int R, int C) {
    __shared__ bf16_t tile[64][66];
    const int tcols = C >> 6;
    const int bx = blockIdx.x % tcols;
    const int by = blockIdx.x / tcols;
    const int c0 = bx << 6, r0 = by << 6;
    const int t = threadIdx.x;
#pragma unroll
    for (int i = 0; i < 16; ++i) {
        int idx = i * 256 + t;
        int rr = idx >> 6, cc = idx & 63;
        tile[rr][cc] = (bf16_t)src[(size_t)(r0 + rr) * C + (c0 + cc)];
    }
    __syncthreads();
#pragma unroll
    for (int i = 0; i < 16; ++i) {
        int idx = i * 256 + t;
        int cc = idx >> 6, rr = idx & 63;
        dst[(size_t)(c0 + cc) * R + (r0 + rr)] = tile[rr][cc];
    }
}

// ---------------------------------------------------------------------------
// 256x256 8-phase GEMM: C(MxN) = A(MxK) @ BT(NxK)^T  [+bias, optional GELU]
// Round-4 schedule (proven correct) with ONE change: the lgkmcnt(0) wait-all
// moved from before-MFMA (which serialized LDS-return + MFMA per wave) to
// just before the closing barrier. Compiler now inserts fine-grained
// lgkmcnt(N) operand waits, overlapping early MFMAs with late ds_read
// returns. WAR safety: all waves drain lgkm before BAR2, and overwriting
// STAGEs are only issued after BAR2.
//
// LIVENESS (per wave: A half = wr, rows read P1(QM0)+P3(QM1); B half = wc>>1,
// read P1+P2; mirrored P5-P7 on buf1):
//   buf0.B free after P2, buf0.A free after P3,
//   buf1.B free after P6, buf1.A free after P7.
// STAGE slots: P1:t1.A1 | P3:t2.B0 | P4:t2.B1,t2.A0 | P5:t2.A1
//              | P7:t3.B0 | P8:t3.B1,t3.A0
// vmcnt ledger (2 loads/STAGE): entry P1 = 6 outstanding (t1.A0,B0,B1);
//   P1:+2=8, P3:+2=10, P4:+4=14, VMW(6) retires 8 = all t0..t1 -> P5 safe;
//   P5:+2=8, P7:+2=10, P8:+4=14, VMW(6) retires 8 = all t2 -> next P1 safe.
// ---------------------------------------------------------------------------
#define BAR() __builtin_amdgcn_s_barrier()
#define LGKM_FENCE() asm volatile("s_waitcnt lgkmcnt(0)" ::: "memory")
#define VMW(n) asm volatile("s_waitcnt vmcnt(" #n ")" ::: "memory")
#define PRIO1() __builtin_amdgcn_s_setprio(1)
#define PRIO0() __builtin_amdgcn_s_setprio(0)

#define DS_A(BUF, QM) do { \
    _Pragma("unroll") for (int mf = 0; mf < 4; ++mf) \
    _Pragma("unroll") for (int ks = 0; ks < 2; ++ks) \
        af[mf][ks] = *(const bf16x8*)&smem[(BUF)*16384 + wr*8192 + (((QM)*4+mf)*2+ks)*512 + lnb_e]; \
} while (0)

#define DS_B(BUF, QN, BB) do { \
    _Pragma("unroll") for (int nf = 0; nf < 2; ++nf) \
    _Pragma("unroll") for (int ks = 0; ks < 2; ++ks) \
        BB[nf][ks] = *(const bf16x8*)&smem[32768 + (BUF)*16384 + bhalf + (((QN)*2+nf)*2+ks)*512 + lnb_e]; \
} while (0)

#define MFMA_Q(QM, QN, BB) do { \
    _Pragma("unroll") for (int ks = 0; ks < 2; ++ks) \
    _Pragma("unroll") for (int mf = 0; mf < 4; ++mf) \
    _Pragma("unroll") for (int nf = 0; nf < 2; ++nf) \
        acc[(QM)*4+mf][(QN)*2+nf] = __builtin_amdgcn_mfma_f32_16x16x32_bf16( \
            af[mf][ks], BB[nf][ks], acc[(QM)*4+mf][(QN)*2+nf], 0, 0, 0); \
} while (0)

// stage one half-tile (128 rows x 64 k = 8192 elems): 2 x global_load_lds/thread
#define STAGE(GBASE, HROWS, TILE, EOFF) do { \
    gload_lds16((GBASE) + aoff0 + (size_t)(HROWS) * K + (TILE) * 64, \
                &smem[(EOFF) + wave * 512]); \
    gload_lds16((GBASE) + aoff1 + (size_t)(HROWS) * K + (TILE) * 64, \
                &smem[(EOFF) + 4096 + wave * 512]); \
} while (0)

template<bool GELU_EPI, int M, int N, int K>
__global__ __launch_bounds__(512, 2)
void gemm8p(const bf16_t* __restrict__ A, const bf16_t* __restrict__ BT,
            const float* __restrict__ bias, void* __restrict__ out)
{
    constexpr int BM = 256, BN = 256;
    constexpr int NT = K / 64, NI = NT / 2;
    constexpr int NBN = N / BN;
    __shared__ __align__(128) bf16_t smem[65536];   // 128 KiB

    const int t = threadIdx.x;
    const int wave = t >> 6, lane = t & 63;
    const int fr = lane & 15, fq = lane >> 4;
    const int wr = wave >> 2, wc = wave & 3;

    int wg = blockIdx.x;
    { const int cpx = (int)gridDim.x >> 3; wg = (wg & 7) * cpx + (wg >> 3); }
    const int bm = wg / NBN, bn = wg % NBN;
    const int rowA0 = bm * BM, colB0 = bn * BN;

    // staging source pre-swizzle: linear LDS byte offset o (within half-tile)
    // -> (row, k):  s=o>>10; ri=(o>>6)&15; b=(o&63)^((ri&8)<<2);
    //               row=(s>>1)*16+ri; k=(s&1)*32+b/2
    int sr0, sk0, sr1, sk1;
    {
        int o = t * 16;
        int ri = (o >> 6) & 15;
        int b = (o & 63) ^ ((ri & 8) << 2);
        sr0 = ((o >> 10) >> 1) * 16 + ri;
        sk0 = ((o >> 10) & 1) * 32 + (b >> 1);
        o = 8192 + t * 16;
        ri = (o >> 6) & 15;
        b = (o & 63) ^ ((ri & 8) << 2);
        sr1 = ((o >> 10) >> 1) * 16 + ri;
        sk1 = ((o >> 10) & 1) * 32 + (b >> 1);
    }
    const bf16_t* gA0 = A + (size_t)rowA0 * K;
    const bf16_t* gB0 = BT + (size_t)colB0 * K;
    const size_t aoff0 = (size_t)sr0 * K + sk0;
    const size_t aoff1 = (size_t)sr1 * K + sk1;

    // read-side swizzled lane base (elements): row fr, k-chunk fq
    const int lnb_e = fr * 32 + ((fq * 8) ^ ((fr & 8) << 1));
    const int bhalf = (wc >> 1) * 8192 + (wc & 1) * 4096;

    f32x4 acc[8][4] = {};
    bf16x8 af[4][2], b0[2][2], b1[2][2];

    // prologue: t0 fully; t1 A0,B0,B1 in flight
    STAGE(gA0, 0,   0, 0);          // t0.A0
    STAGE(gA0, 128, 0, 8192);       // t0.A1
    STAGE(gB0, 0,   0, 32768);      // t0.B0
    STAGE(gB0, 128, 0, 40960);      // t0.B1
    STAGE(gA0, 0,   1, 16384);      // t1.A0
    STAGE(gB0, 0,   1, 49152);      // t1.B0
    STAGE(gB0, 128, 1, 57344);      // t1.B1
    VMW(6);                         // t0 landed; t1 (6 loads) may fly
    BAR();

    for (int i = 0; i < NI - 1; ++i) {
        const int t1 = 2 * i + 1, t2 = 2 * i + 2, t3 = 2 * i + 3;
        // P1: Q00 on buf0
        DS_A(0, 0); DS_B(0, 0, b0);
        STAGE(gA0, 128, t1, 24576);            // buf1.A1 <- t1.A1
        BAR();
        PRIO1(); MFMA_Q(0, 0, b0); PRIO0();
        LGKM_FENCE();
        BAR();
        // P2: Q01 (no stage; buf0.B live until end of P2)
        DS_B(0, 1, b1);
        BAR();
        PRIO1(); MFMA_Q(0, 1, b1); PRIO0();
        LGKM_FENCE();
        BAR();
        // P3: Q11 (buf0.B free after P2)
        DS_A(0, 1);
        STAGE(gB0, 0, t2, 32768);              // buf0.B0 <- t2.B0
        BAR();
        PRIO1(); MFMA_Q(1, 1, b1); PRIO0();
        LGKM_FENCE();
        BAR();
        // P4: Q10 regs-only (buf0.A free after P3)
        STAGE(gB0, 128, t2, 40960);            // buf0.B1 <- t2.B1
        STAGE(gA0, 0,   t2, 0);                // buf0.A0 <- t2.A0
        VMW(6);                                // t1 fully landed
        BAR();
        PRIO1(); MFMA_Q(1, 0, b0); PRIO0();
        BAR();
        // P5: Q00 on buf1
        DS_A(1, 0); DS_B(1, 0, b0);
        STAGE(gA0, 128, t2, 8192);             // buf0.A1 <- t2.A1
        BAR();
        PRIO1(); MFMA_Q(0, 0, b0); PRIO0();
        LGKM_FENCE();
        BAR();
        // P6: Q01
        DS_B(1, 1, b1);
        BAR();
        PRIO1(); MFMA_Q(0, 1, b1); PRIO0();
        LGKM_FENCE();
        BAR();
        // P7: Q11 (buf1.B free after P6)
        DS_A(1, 1);
        STAGE(gB0, 0, t3, 49152);              // buf1.B0 <- t3.B0
        BAR();
        PRIO1(); MFMA_Q(1, 1, b1); PRIO0();
        LGKM_FENCE();
        BAR();
        // P8: Q10 (buf1.A free after P7)
        STAGE(gB0, 128, t3, 57344);            // buf1.B1 <- t3.B1
        STAGE(gA0, 0,   t3, 16384);            // buf1.A0 <- t3.A0
        VMW(6);                                // t2 fully landed
        BAR();
        PRIO1(); MFMA_Q(1, 0, b0); PRIO0();
        BAR();
    }

    // peeled last iteration: tile NT-2 in buf0, NT-1 in buf1
    DS_A(0, 0); DS_B(0, 0, b0);
    STAGE(gA0, 128, NT - 1, 24576);            // buf1.A1 <- (NT-1).A1
    BAR();
    PRIO1(); MFMA_Q(0, 0, b0); PRIO0();
    LGKM_FENCE();
    BAR();
    DS_B(0, 1, b1);
    BAR();
    PRIO1(); MFMA_Q(0, 1, b1); PRIO0();
    LGKM_FENCE();
    BAR();
    DS_A(0, 1);
    BAR();
    PRIO1(); MFMA_Q(1, 1, b1); PRIO0();
    LGKM_FENCE();
    BAR();
    VMW(0);                                    // drain: buf1 complete
    BAR();
    PRIO1(); MFMA_Q(1, 0, b0); PRIO0();
    BAR();
    DS_A(1, 0); DS_B(1, 0, b0);
    BAR();
    PRIO1(); MFMA_Q(0, 0, b0); PRIO0();
    LGKM_FENCE();
    BAR();
    DS_B(1, 1, b1);
    BAR();
    PRIO1(); MFMA_Q(0, 1, b1); PRIO0();
    LGKM_FENCE();
    BAR();
    DS_A(1, 1);
    BAR();
    PRIO1(); MFMA_Q(1, 1, b1); PRIO0();
    MFMA_Q(1, 0, b0);

    // epilogue: C/D layout col=lane&15, row=(lane>>4)*4+reg
    const int orow = rowA0 + wr * 128 + fq * 4;
    const int ocol = colB0 + wc * 64 + fr;
#pragma unroll
    for (int mf = 0; mf < 8; ++mf) {
#pragma unroll
        for (int nf = 0; nf < 4; ++nf) {
            const int c = ocol + nf * 16;
            const float bv = bias[c];
#pragma unroll
            for (int v = 0; v < 4; ++v) {
                const int r = orow + mf * 16 + v;
                float xv = acc[mf][nf][v] + bv;
                if constexpr (GELU_EPI) {
                    float g = 0.5f * xv * (1.0f + erff(xv * 0.70710678118654752f));
                    ((bf16_t*)out)[(size_t)r * N + c] = (bf16_t)g;
                } else {
                    ((float*)out)[(size_t)r * N + c] = xv;
                }
            }
        }
    }
}

// ---------------------------------------------------------------------------
// launch
// ---------------------------------------------------------------------------
extern "C" void kernel_launch(void* const* d_in, const int* in_sizes, int n_in,
                              void* d_out, int out_size, void* d_ws, size_t ws_size,
                              hipStream_t stream) {
    const float* x  = (const float*)d_in[0];
    const float* w1 = (const float*)d_in[1];
    const float* b1 = (const float*)d_in[2];
    const float* w2 = (const float*)d_in[3];
    const float* b2 = (const float*)d_in[4];
    float* y = (float*)d_out;

    const size_t xb_elems  = (size_t)TOKENS * HIDDEN;
    const size_t w1t_elems = (size_t)FFN * HIDDEN;
    const size_t w2t_elems = (size_t)HIDDEN * FFN;
    const size_t h_elems   = (size_t)TOKENS * FFN;
    const size_t need = (xb_elems + w1t_elems + w2t_elems + h_elems) * sizeof(bf16_t);
    if (ws_size < need) return;

    char* ws = (char*)d_ws;
    bf16_t* xb  = (bf16_t*)ws;
    bf16_t* w1t = xb + xb_elems;
    bf16_t* w2t = w1t + w1t_elems;
    bf16_t* h   = w2t + w2t_elems;

    cvt_f32_to_bf16<<<(TOKENS * HIDDEN / 8 + 255) / 256, 256, 0, stream>>>(
        x, xb, TOKENS * HIDDEN / 8);
    transpose_cvt<<<(HIDDEN / 64) * (FFN / 64), 256, 0, stream>>>(w1, w1t, HIDDEN, FFN);
    transpose_cvt<<<(FFN / 64) * (HIDDEN / 64), 256, 0, stream>>>(w2, w2t, FFN, HIDDEN);

    gemm8p<true, TOKENS, FFN, HIDDEN>
        <<<(TOKENS / 256) * (FFN / 256), 512, 0, stream>>>(xb, w1t, b1, h);
    gemm8p<false, TOKENS, HIDDEN, FFN>
        <<<(TOKENS / 256) * (HIDDEN / 256), 512, 0, stream>>>(h, w2t, b2, y);
}